// Round 11
// baseline (349.152 us; speedup 1.0000x reference)
//
#include <hip/hip_runtime.h>

// Dtypes (established round 5): inputs int32/f32, outputs f32 (gid, score).
#define SS 4
#define BB 256
#define PP 32768
#define DD 256
#define QQ 1024          // SS*BB
#define NN 131072        // SS*PP candidate rows
#define KTOP 10
#define QTILE 128        // queries per block (4 waves x 32 q)
#define WQ 32            // q per wave (32x32 MFMA)
#define NCHUNK 64        // n-chunks
#define CHROWS 2048      // rows per chunk
#define PANEL 64         // rows per LDS panel
#define NPANEL (CHROWS / PANEL)   // 32
#define JCH 8            // per-(q,chunk) survivors (sorted desc run)
#define MSLOT 20         // global approx survivors per q (exact-rescored)
#define ROWG 33          // padded LDS row stride in 16B granules
#define ROWE (ROWG * 8)  // row stride in bf16 units (264)
#define PANB (PANEL * ROWG * 16)  // 33792 B per panel buffer
#define KEYMASK 0xFFFFF800u       // keep 21 score bits, low 11 = column
#define MWS 132          // merge-stage row stride in u32 (bank-spread, 16B-aligned)

typedef __attribute__((ext_vector_type(8))) short bf16x8;
typedef __attribute__((ext_vector_type(4))) float f32x4;
typedef __attribute__((ext_vector_type(16))) float f32x16;
typedef __attribute__((ext_vector_type(4))) unsigned int u32x4;

static __device__ __forceinline__ short f2bf(float f) {   // RNE (qvec only)
    union { float f; unsigned u; } v; v.f = f;
    unsigned r = (v.u + 0x7FFFu + ((v.u >> 16) & 1u)) >> 16;
    return (short)r;
}
// truncation-pack two f32 -> one u32 of two bf16 (lo in low16, hi in high16)
static __device__ __forceinline__ unsigned pk2(float lo, float hi) {
    return (__float_as_uint(hi) & 0xFFFF0000u) | (__float_as_uint(lo) >> 16);
}
static __device__ __forceinline__ u32x4 pk8(f32x4 a, f32x4 b) {
    u32x4 g;
    g[0] = pk2(a[0], a[1]); g[1] = pk2(a[2], a[3]);
    g[2] = pk2(b[0], b[1]); g[3] = pk2(b[2], b[3]);
    return g;
}
static __device__ __forceinline__ unsigned umax(unsigned a, unsigned b) { return a > b ? a : b; }
static __device__ __forceinline__ unsigned umin(unsigned a, unsigned b) { return a < b ? a : b; }

// ---------------- Stage 0: qvec = E[s1,head]*R[rel] (f32 exact) -> bf16 RNE ---------------
__global__ void qvec_kernel(const int* __restrict__ rel, const int* __restrict__ head,
                            const float* __restrict__ E, const float* __restrict__ R,
                            short* __restrict__ qbf) {
    int q = blockIdx.x, d = threadIdx.x;
    int s1 = q >> 8;
    float f = E[((size_t)(s1 * PP + head[q])) * DD + d] * R[(size_t)rel[q] * DD + d];
    qbf[q * DD + d] = f2bf(f);
}

// ---------------- Stage 1: 32x32x16 bf16 MFMA (dual chains), inline f32->bf16 staging -----
__launch_bounds__(256, 2)
__global__ void score_topk_kernel(const float* __restrict__ E, const short* __restrict__ qbf,
                                  unsigned* __restrict__ parts) {
    // LDS: 2 x panel buffers (64 rows x 33 granules x 16B) = 67584 B.
    // End-merge reuses the region: 4 waves x 32 q x 132-u32 stride = 67584 B.
    __shared__ __align__(16) char smem[2 * PANB];

    const int tid  = threadIdx.x;
    const int wave = tid >> 6;
    const int lane = tid & 63;
    const int lh   = lane >> 5;   // k-half
    const int ln   = lane & 31;
    const int mtile = blockIdx.x >> 6;   // 0..7
    const int chunk = blockIdx.x & 63;   // 0..63

    short* buf0 = (short*)smem;
    short* buf1 = (short*)(smem + PANB);

    // A fragments: A[m=lane&31][k=ks*16 + (lane>>5)*8 + j]
    bf16x8 afrag[16];
    {
        const int arow = mtile * QTILE + wave * WQ + ln;
        #pragma unroll
        for (int ks = 0; ks < 16; ks++)
            afrag[ks] = *(const bf16x8*)(qbf + arow * DD + ks * 16 + lh * 8);
    }

    // 16 per-lane 4-deep ascending lists; list r holds q_local=(r&3)+8*(r>>2)+4*lh
    unsigned lst[16][4];
    #pragma unroll
    for (int r = 0; r < 16; r++)
        #pragma unroll
        for (int i = 0; i < 4; i++) lst[r][i] = 0u;

    const int n0c = chunk * CHROWS;

    // prologue: stage panel 0 into buf0 (2048 granules / 256 threads = 8 each; f32 source)
    f32x4 sa[8], sb[8];
    #pragma unroll
    for (int it = 0; it < 8; it++) {
        int gi = it * 256 + tid, row = gi >> 5, slot = gi & 31;
        const float* src = E + (size_t)(n0c + row) * DD + slot * 8;
        sa[it] = *(const f32x4*)(src);
        sb[it] = *(const f32x4*)(src + 4);
    }
    #pragma unroll
    for (int it = 0; it < 8; it++) {
        int gi = it * 256 + tid, row = gi >> 5, slot = gi & 31;
        *(u32x4*)(buf0 + row * ROWE + slot * 8) = pk8(sa[it], sb[it]);
    }

    for (int p = 0; p < NPANEL; p++) {
        short* bp = (p & 1) ? buf1 : buf0;
        short* bn = (p & 1) ? buf0 : buf1;
        __syncthreads();
        if (p + 1 < NPANEL) {   // prefetch next panel (overlaps compute)
            const int n1 = n0c + (p + 1) * PANEL;
            #pragma unroll
            for (int it = 0; it < 8; it++) {
                int gi = it * 256 + tid, row = gi >> 5, slot = gi & 31;
                const float* src = E + (size_t)(n1 + row) * DD + slot * 8;
                sa[it] = *(const f32x4*)(src);
                sb[it] = *(const f32x4*)(src + 4);
            }
        }

        // two independent accumulator chains (cols ln and 32+ln), +256 bias in C init
        f32x16 acc0, acc1;
        #pragma unroll
        for (int r = 0; r < 16; r++) { acc0[r] = 256.0f; acc1[r] = 256.0f; }
        const short* b0 = bp + ln * ROWE + lh * 8;
        const short* b1 = bp + (32 + ln) * ROWE + lh * 8;
        #pragma unroll
        for (int ks = 0; ks < 16; ks++) {
            bf16x8 x0 = *(const bf16x8*)(b0 + ks * 16);
            bf16x8 x1 = *(const bf16x8*)(b1 + ks * 16);
            acc0 = __builtin_amdgcn_mfma_f32_32x32x16_bf16(afrag[ks], x0, acc0, 0, 0, 0);
            acc1 = __builtin_amdgcn_mfma_f32_32x32x16_bf16(afrag[ks], x1, acc1, 0, 0, 0);
        }

        // D: col=lane&31, row=(reg&3)+8*(reg>>2)+4*lh -> one key per owned (q,col)
        const unsigned c0 = (unsigned)(p * 64 + ln);
        const unsigned c1 = (unsigned)(p * 64 + 32 + ln);
        #pragma unroll
        for (int r = 0; r < 16; r++) {
            unsigned key = (__float_as_uint(acc0[r]) & KEYMASK) | c0;
            unsigned n0 = umin(umax(key, lst[r][0]), lst[r][1]);
            unsigned n1 = umin(umax(key, lst[r][1]), lst[r][2]);
            unsigned n2 = umin(umax(key, lst[r][2]), lst[r][3]);
            unsigned n3 = umax(key, lst[r][3]);
            lst[r][0] = n0; lst[r][1] = n1; lst[r][2] = n2; lst[r][3] = n3;
        }
        #pragma unroll
        for (int r = 0; r < 16; r++) {
            unsigned key = (__float_as_uint(acc1[r]) & KEYMASK) | c1;
            unsigned n0 = umin(umax(key, lst[r][0]), lst[r][1]);
            unsigned n1 = umin(umax(key, lst[r][1]), lst[r][2]);
            unsigned n2 = umin(umax(key, lst[r][2]), lst[r][3]);
            unsigned n3 = umax(key, lst[r][3]);
            lst[r][0] = n0; lst[r][1] = n1; lst[r][2] = n2; lst[r][3] = n3;
        }

        if (p + 1 < NPANEL) {
            #pragma unroll
            for (int it = 0; it < 8; it++) {
                int gi = it * 256 + tid, row = gi >> 5, slot = gi & 31;
                *(u32x4*)(bn + row * ROWE + slot * 8) = pk8(sa[it], sb[it]);
            }
        }
    }

    // ---- end of chunk: per-wave dump (32 q x 128 keys), lanes<32 build top-8 runs ----
    __syncthreads();   // all panel reads complete; reuse whole smem
    unsigned* mw = (unsigned*)smem + (size_t)wave * (WQ * MWS);
    #pragma unroll
    for (int r = 0; r < 16; r++) {
        int q = (r & 3) + 8 * (r >> 2) + 4 * lh;
        u32x4 v; v[0] = lst[r][0]; v[1] = lst[r][1]; v[2] = lst[r][2]; v[3] = lst[r][3];
        *(u32x4*)(mw + q * MWS + ln * 4) = v;   // same-wave LDS, program-order visible
    }
    if (lane < 32) {   // lane = q_local: top-8 of its 128 keys
        unsigned rr[JCH];
        #pragma unroll
        for (int i = 0; i < JCH; i++) rr[i] = 0u;
        #pragma unroll
        for (int j = 0; j < 32; j++) {
            u32x4 v = *(const u32x4*)(mw + lane * MWS + j * 4);
            #pragma unroll
            for (int e = 0; e < 4; e++) {
                unsigned x = v[e];
                unsigned t0 = umin(umax(x, rr[0]), rr[1]);
                unsigned t1 = umin(umax(x, rr[1]), rr[2]);
                unsigned t2 = umin(umax(x, rr[2]), rr[3]);
                unsigned t3 = umin(umax(x, rr[3]), rr[4]);
                unsigned t4 = umin(umax(x, rr[4]), rr[5]);
                unsigned t5 = umin(umax(x, rr[5]), rr[6]);
                unsigned t6 = umin(umax(x, rr[6]), rr[7]);
                unsigned t7 = umax(x, rr[7]);
                rr[0]=t0; rr[1]=t1; rr[2]=t2; rr[3]=t3; rr[4]=t4; rr[5]=t5; rr[6]=t6; rr[7]=t7;
            }
        }
        const int qg = mtile * QTILE + wave * WQ + lane;
        unsigned* dst = parts + ((size_t)qg * NCHUNK + chunk) * JCH;
        #pragma unroll
        for (int i = 0; i < JCH; i++) dst[i] = rr[JCH - 1 - i];   // descending run
    }
}

// ---------------- Stage 2: fused merge (lane=chunk, 20 pops) + exact f32 rescore ----------
__global__ void finalize_kernel(const int* __restrict__ rel, const int* __restrict__ head,
                                const float* __restrict__ E, const float* __restrict__ R,
                                const unsigned* __restrict__ parts, float* __restrict__ out) {
    __shared__ float qv[DD];
    __shared__ int   gl[MSLOT];
    __shared__ float rsc[MSLOT];
    __shared__ int   rgid[MSLOT];

    const int q = blockIdx.x;
    const int tid = threadIdx.x;
    const int wave = tid >> 6, lane = tid & 63;
    const int s1 = q >> 8;

    qv[tid] = E[((size_t)(s1 * PP + head[q])) * DD + tid] * R[(size_t)rel[q] * DD + tid];

    if (wave == 0) {   // lane = chunk; 20 argmax-pops over 64 sorted-desc runs of 8
        unsigned run[JCH];
        const unsigned* src = parts + ((size_t)q * NCHUNK + lane) * JCH;
        #pragma unroll
        for (int j = 0; j < JCH; j++) run[j] = src[j];
        for (int r = 0; r < MSLOT; r++) {
            unsigned best = run[0]; int bl = lane;
            #pragma unroll
            for (int off = 32; off >= 1; off >>= 1) {
                unsigned ob = __shfl_xor(best, off);
                int ol = __shfl_xor(bl, off);
                if (ob > best || (ob == best && ol < bl)) { best = ob; bl = ol; }
            }
            if (lane == bl) {
                int col = (int)(best & 0x7FFu);
                int n = lane * CHROWS + col;
                gl[r] = ((n & (PP - 1)) << 2) | (n >> 15);   // gid = p*4 + s2
                #pragma unroll
                for (int j = 0; j < JCH - 1; j++) run[j] = run[j + 1];
                run[JCH - 1] = 0u;
            }
        }
    }
    __syncthreads();

    // exact f32 rescore: wave w handles candidates w*5 .. w*5+4
    f32x4 qq = *(const f32x4*)(qv + lane * 4);
    #pragma unroll
    for (int c = 0; c < MSLOT / 4; c++) {
        int j = wave * (MSLOT / 4) + c;
        int gid = gl[j];
        int n = (gid & 3) * PP + (gid >> 2);
        f32x4 ev = *(const f32x4*)(E + (size_t)n * DD + lane * 4);
        f32x4 p = qq * ev;
        float s = (p[0] + p[1]) + (p[2] + p[3]);
        #pragma unroll
        for (int off = 32; off >= 1; off >>= 1) s += __shfl_xor(s, off);
        if (lane == 0) { rsc[j] = s; rgid[j] = gid; }
    }
    __syncthreads();

    if (tid < 64) {   // wave 0: 10 argmax-pops over 20 exact scores
        float a = (tid < MSLOT) ? rsc[tid] : -1e30f;
        int   g = (tid < MSLOT) ? rgid[tid] : 0;
        for (int r = 0; r < KTOP; r++) {
            float ps = a; int pg = g; int plm = tid;
            #pragma unroll
            for (int off = 32; off >= 1; off >>= 1) {
                float os = __shfl_xor(ps, off);
                int   og = __shfl_xor(pg, off);
                int   ol = __shfl_xor(plm, off);
                if (os > ps || (os == ps && ol < plm)) { ps = os; pg = og; plm = ol; }
            }
            if (tid == 0) {
                out[q * KTOP + r]             = (float)pg;   // Output 0: gid
                out[QQ * KTOP + q * KTOP + r] = ps;          // Output 1: score
            }
            if (tid == plm) a = -1e30f;
        }
    }
}

extern "C" void kernel_launch(void* const* d_in, const int* in_sizes, int n_in,
                              void* d_out, int out_size, void* d_ws, size_t ws_size,
                              hipStream_t stream) {
    const int*   rel  = (const int*)d_in[0];
    const int*   head = (const int*)d_in[1];
    const float* E    = (const float*)d_in[2];
    const float* R    = (const float*)d_in[3];

    char* ws = (char*)d_ws;
    short* qbf = (short*)ws;                                   //   524,288 B
    unsigned* parts = (unsigned*)(ws + (size_t)QQ * DD * 2);   // 2,097,152 B

    qvec_kernel<<<dim3(QQ), dim3(DD), 0, stream>>>(rel, head, E, R, qbf);
    score_topk_kernel<<<dim3((QQ / QTILE) * NCHUNK), dim3(256), 0, stream>>>(E, qbf, parts);
    finalize_kernel<<<dim3(QQ), dim3(256), 0, stream>>>(rel, head, E, R, parts, (float*)d_out);
}